// Round 9
// baseline (313.553 us; speedup 1.0000x reference)
//
#include <hip/hip_runtime.h>

#define DDIM 1024
#define NEXP 64
#define TOPK 8
#define BK 32
#define NTILE 32
#define WTILE 12288
#define TAUF 5.0e-3f
#define TAUB 1.0e-2f
#define WSLOG_OFF (512 * 1024)

typedef __attribute__((ext_vector_type(8))) short short8;
typedef __attribute__((ext_vector_type(4))) float f32x4;

static __device__ __forceinline__ unsigned int f2u(float f) { return __builtin_bit_cast(unsigned int, f); }
static __device__ __forceinline__ float u2f(unsigned int u) { return __builtin_bit_cast(float, u); }

static __device__ __forceinline__ unsigned short bf_hi_rne(float x) {
    unsigned int u = f2u(x);
    return (unsigned short)((u + (0x7FFFu + ((u >> 16) & 1u))) >> 16);
}

static __device__ __forceinline__ void split2(float x, unsigned short& h, unsigned short& l) {
    unsigned int u = f2u(x);
    unsigned int uh = (u + (0x7FFFu + ((u >> 16) & 1u))) & 0xFFFF0000u;
    h = (unsigned short)(uh >> 16);
    float rem = x - u2f(uh);
    l = (unsigned short)(f2u(rem) >> 16);
}

// K1: pre-permute W into the swizzled LDS image (proven R6 layout), DMA/copy'd linearly.
// tile t, array a (0=wn_hi,1=wn_lo,2=we_hi), expert e, 16B chunk c:
//   ws byte = t*12288 + a*4096 + ((e*64 + c*16) ^ ((e&7)<<4))
__global__ __launch_bounds__(256) void conv_w_kernel(
    const float* __restrict__ Wn, const float* __restrict__ We, char* __restrict__ wsW)
{
    int g = blockIdx.x * 256 + threadIdx.x;   // 0..8191
    int e = g >> 7, c128 = g & 127;
    int k = c128 << 3;
    int t = k >> 5, c = (k >> 3) & 3;
    const float* np = Wn + (size_t)e * DDIM + k;
    const float* ep = We + (size_t)e * DDIM + k;
    f32x4 n0 = ((const f32x4*)np)[0], n1 = ((const f32x4*)np)[1];
    f32x4 e0 = ((const f32x4*)ep)[0], e1 = ((const f32x4*)ep)[1];
    short8 nh, nl, eh;
#pragma unroll
    for (int i = 0; i < 4; i++) { unsigned short h, l; split2(n0[i], h, l); nh[i] = (short)h; nl[i] = (short)l; }
#pragma unroll
    for (int i = 0; i < 4; i++) { unsigned short h, l; split2(n1[i], h, l); nh[i + 4] = (short)h; nl[i + 4] = (short)l; }
#pragma unroll
    for (int i = 0; i < 4; i++) eh[i] = (short)bf_hi_rne(e0[i]);
#pragma unroll
    for (int i = 0; i < 4; i++) eh[i + 4] = (short)bf_hi_rne(e1[i]);
    size_t dst = (size_t)t * WTILE + (size_t)((e * 64 + c * 16) ^ ((e & 7) << 4));
    *(short8*)(wsW + dst)        = nh;
    *(short8*)(wsW + dst + 4096) = nl;
    *(short8*)(wsW + dst + 8192) = eh;
}

// ---- shared epilogue: wave-parallel top-8 + softmax + weighted sum + fp64 fixup (reg-only)
static __device__ __forceinline__ float wave_maxf(float c) {
#pragma unroll
    for (int off = 32; off >= 1; off >>= 1) c = fmaxf(c, __shfl_xor(c, off));
    return c;
}
static __device__ __forceinline__ float wave_sumf(float c) {
#pragma unroll
    for (int off = 32; off >= 1; off >>= 1) c += __shfl_xor(c, off);
    return c;
}

static __device__ __forceinline__ void process_row(
    int r, float v, float g, int lane,
    const float* __restrict__ x, const float* __restrict__ Wn,
    const float* __restrict__ bn, float* __restrict__ out)
{
    for (int pass = 0; pass < 2; ++pass) {
        unsigned long long act = ~0ull, sel = 0ull;
        float m0 = 0.f, v8 = 0.f;
#pragma unroll
        for (int tt = 0; tt < TOPK; tt++) {
            float c = ((act >> lane) & 1ull) ? v : -3.0e38f;
            c = wave_maxf(c);
            unsigned long long elig = __ballot(v == c) & act;   // lowest index wins ties
            int win = __builtin_ctzll(elig);
            sel |= 1ull << win;
            act &= ~(1ull << win);
            if (tt == 0) m0 = c;
            v8 = c;
        }
        float c9 = ((act >> lane) & 1ull) ? v : -3.0e38f;
        float v9 = wave_maxf(c9);

        if (pass == 0 && (v8 - v9) < TAUF) {
            // fp64 fixup: recompute boundary-band candidate logits exactly
            const float vb = 0.5f * (v8 + v9);
            unsigned long long cand = __ballot(fabsf(v - vb) <= TAUB);
            const f32x4* xq = (const f32x4*)(x + (size_t)r * DDIM) + lane * 4;
            const f32x4 xv0 = xq[0], xv1 = xq[1], xv2 = xq[2], xv3 = xq[3];
            while (cand) {
                const int ce = __builtin_ctzll(cand);
                cand &= cand - 1;
                const f32x4* wq = (const f32x4*)(Wn + (size_t)ce * DDIM) + lane * 4;
                const f32x4 w0 = wq[0], w1 = wq[1], w2 = wq[2], w3 = wq[3];
                double s = 0.0;
#pragma unroll
                for (int i = 0; i < 4; i++) s = fma((double)xv0[i], (double)w0[i], s);
#pragma unroll
                for (int i = 0; i < 4; i++) s = fma((double)xv1[i], (double)w1[i], s);
#pragma unroll
                for (int i = 0; i < 4; i++) s = fma((double)xv2[i], (double)w2[i], s);
#pragma unroll
                for (int i = 0; i < 4; i++) s = fma((double)xv3[i], (double)w3[i], s);
#pragma unroll
                for (int off = 32; off > 0; off >>= 1) s += __shfl_xor(s, off);
                s += (double)bn[ce];
                if (lane == ce) v = (float)s;
            }
            continue;   // pass 1 re-selects with corrected v
        }
        float w = ((sel >> lane) & 1ull) ? __expf(v - m0) : 0.f;
        float Z = wave_sumf(w);
        float O = wave_sumf(w * g);
        if (lane == 0) out[r] = O / Z;
        return;
    }
}

// K2: GEMM only. 64 rows/block, 1024 blocks, 256 thr. LDS exactly 32768 B -> 5 blocks/CU.
//   x dbuf [2][64][32]bf16 @0 (4KB each, XOR-swizzled); W dbuf [2][12288] @8192.
//   Pipeline: CP(t) -> SW(t+1) -> XL(t+4, 3 sets) -> WL(t+3, 2 sets) -> lgkm(0)+barrier.
//   Loads issued before next iter's SW => compiler emits counted vmcnt(5), never a drain.
__global__ __launch_bounds__(256, 5) void gemm_kernel(
    const float* __restrict__ x, const char* __restrict__ wsW,
    float* __restrict__ ws_log, float* __restrict__ ws_exp)
{
    __shared__ __align__(16) char smem[32768];

    const int tid = threadIdx.x;
    const int wid = tid >> 6;
    const int lane = tid & 63;
    const int fr = lane & 15;
    const int fq = lane >> 4;
    const int blockRow = blockIdx.x * 64;

    // x stage role: thread covers row srow, 8-float chunk sg (coalesced 128B/row)
    const int srow = tid >> 2, sg = tid & 3;
    const int swz = (srow * 64 + sg * 16) ^ ((srow & 7) << 4);
    const float* xsrc = x + (size_t)(blockRow + srow) * DDIM + sg * 8;
    // W stage role: thread copies bytes [tid*16, tid*16+16) of each 4KB array (image = ws image)
    const char* wsrc = wsW + tid * 16;

    const int ecol = wid * 16 + fr;
    const int woff = (ecol * 64 + fq * 16) ^ ((ecol & 7) << 4);

    f32x4 xA0, xA1, xB0, xB1, xC0, xC1;          // 3 named x sets
    short8 wA0, wA1, wA2, wB0, wB1, wB2;         // 2 named W sets

    f32x4 accN[4], accE[4];
#pragma unroll
    for (int rt = 0; rt < 4; rt++) { accN[rt] = f32x4{0.f,0.f,0.f,0.f}; accE[rt] = f32x4{0.f,0.f,0.f,0.f}; }

#define XL(S, T) { const float* p_ = xsrc + (T) * BK; \
    x##S##0 = ((const f32x4*)p_)[0]; x##S##1 = ((const f32x4*)p_)[1]; }
#define WL(S, T) { const char* q_ = wsrc + (size_t)(T) * WTILE; \
    w##S##0 = *(const short8*)(q_); \
    w##S##1 = *(const short8*)(q_ + 4096); \
    w##S##2 = *(const short8*)(q_ + 8192); }
#define SW(B, XS, WS) { short8 h_; \
    _Pragma("unroll") for (int i = 0; i < 4; i++) h_[i]     = (short)bf_hi_rne(x##XS##0[i]); \
    _Pragma("unroll") for (int i = 0; i < 4; i++) h_[i + 4] = (short)bf_hi_rne(x##XS##1[i]); \
    *(short8*)(smem + (B) * 4096 + swz) = h_; \
    char* wb_ = smem + 8192 + (B) * WTILE + tid * 16; \
    *(short8*)(wb_)        = w##WS##0; \
    *(short8*)(wb_ + 4096) = w##WS##1; \
    *(short8*)(wb_ + 8192) = w##WS##2; }
#define CP(B) { const char* wb_ = smem + 8192 + (B) * WTILE + woff; \
    short8 wh_ = *(const short8*)(wb_); \
    short8 wl_ = *(const short8*)(wb_ + 4096); \
    short8 eh_ = *(const short8*)(wb_ + 8192); \
    _Pragma("unroll") \
    for (int rt = 0; rt < 4; rt++) { \
        const int row_ = rt * 16 + fr; \
        const int xoff_ = (row_ * 64 + fq * 16) ^ ((row_ & 7) << 4); \
        short8 xh_ = *(const short8*)(smem + (B) * 4096 + xoff_); \
        accN[rt] = __builtin_amdgcn_mfma_f32_16x16x32_bf16(xh_, wh_, accN[rt], 0, 0, 0); \
        accN[rt] = __builtin_amdgcn_mfma_f32_16x16x32_bf16(xh_, wl_, accN[rt], 0, 0, 0); \
        accE[rt] = __builtin_amdgcn_mfma_f32_16x16x32_bf16(xh_, eh_, accE[rt], 0, 0, 0); \
    } }
#define BARR { asm volatile("s_waitcnt lgkmcnt(0)" ::: "memory"); \
               __builtin_amdgcn_s_barrier(); \
               asm volatile("" ::: "memory"); }

#define ITER(T, XS, WS, DOX, DOW) { \
    CP((T) & 1) \
    SW(((T) + 1) & 1, XS, WS) \
    if (DOX) { XL(XS, (T) + 4) } \
    if (DOW) { WL(WS, (T) + 3) } \
    BARR }

    // prologue
    XL(A, 0) XL(B, 1) XL(C, 2) WL(A, 0) WL(B, 1)
    SW(0, A, A)
    XL(A, 3) WL(A, 2)
    BARR

    ITER(0,  B, B, 1, 1) ITER(1,  C, A, 1, 1) ITER(2,  A, B, 1, 1)
    ITER(3,  B, A, 1, 1) ITER(4,  C, B, 1, 1) ITER(5,  A, A, 1, 1)
    ITER(6,  B, B, 1, 1) ITER(7,  C, A, 1, 1) ITER(8,  A, B, 1, 1)
    ITER(9,  B, A, 1, 1) ITER(10, C, B, 1, 1) ITER(11, A, A, 1, 1)
    ITER(12, B, B, 1, 1) ITER(13, C, A, 1, 1) ITER(14, A, B, 1, 1)
    ITER(15, B, A, 1, 1) ITER(16, C, B, 1, 1) ITER(17, A, A, 1, 1)
    ITER(18, B, B, 1, 1) ITER(19, C, A, 1, 1) ITER(20, A, B, 1, 1)
    ITER(21, B, A, 1, 1) ITER(22, C, B, 1, 1) ITER(23, A, A, 1, 1)
    ITER(24, B, B, 1, 1) ITER(25, C, A, 1, 1) ITER(26, A, B, 1, 1)
    ITER(27, B, A, 1, 1) ITER(28, C, B, 0, 1) ITER(29, A, A, 0, 0)
    ITER(30, B, B, 0, 0)
    CP(1)                         // tile 31
    __syncthreads();

    // transpose via LDS overlay, then coalesced f32 stores of logits/evals
    float* sl = (float*)smem;                    // [64][64]
    float* se = (float*)(smem + 16384);          // [64][64]
#pragma unroll
    for (int rt = 0; rt < 4; rt++) {
#pragma unroll
        for (int j = 0; j < 4; j++) {
            const int r = rt * 16 + fq * 4 + j;  // C/D: col=lane&15, row=(lane>>4)*4+j
            sl[r * 64 + ecol] = accN[rt][j];
            se[r * 64 + ecol] = accE[rt][j];
        }
    }
    __syncthreads();
    {
        const int row = tid >> 2, cg = (tid & 3) * 16;
        float* gl = ws_log + (size_t)(blockRow + row) * 64 + cg;
        float* ge = ws_exp + (size_t)(blockRow + row) * 64 + cg;
#pragma unroll
        for (int i = 0; i < 4; i++) ((f32x4*)gl)[i] = *(const f32x4*)(sl + row * 64 + cg + i * 4);
#pragma unroll
        for (int i = 0; i < 4; i++) ((f32x4*)ge)[i] = *(const f32x4*)(se + row * 64 + cg + i * 4);
    }
}

// K3: selection + fixup, register-only. 512 blocks x 256 thr; wave handles 32 rows.
__global__ __launch_bounds__(256) void select_kernel(
    const float* __restrict__ x, const float* __restrict__ Wn, const float* __restrict__ bn,
    const float* __restrict__ ws_log, const float* __restrict__ ws_exp, float* __restrict__ out)
{
    const int wid = threadIdx.x >> 6, lane = threadIdx.x & 63;
    const int base = blockIdx.x * 128 + wid * 32;
    const float be = bn[lane];
    for (int rr = 0; rr < 32; ++rr) {
        const int r = base + rr;
        const float v = ws_log[(size_t)r * 64 + lane] + be;
        const float g = ws_exp[(size_t)r * 64 + lane];
        process_row(r, v, g, lane, x, Wn, bn, out);
    }
}

// Fallback (ws too small): exact fp64 per-row computation. Slow but correct.
__global__ __launch_bounds__(256) void fused_fallback(
    const float* __restrict__ x, const float* __restrict__ Wn, const float* __restrict__ bn,
    const float* __restrict__ We, float* __restrict__ out, int B)
{
    const int wid = threadIdx.x >> 6, lane = threadIdx.x & 63;
    const int r = blockIdx.x * 4 + wid;
    if (r >= B) return;
    const f32x4* xq = (const f32x4*)(x + (size_t)r * DDIM) + lane * 4;
    const f32x4 xv0 = xq[0], xv1 = xq[1], xv2 = xq[2], xv3 = xq[3];
    float v = 0.f, g = 0.f;
    for (int e = 0; e < NEXP; ++e) {
        const f32x4* wq = (const f32x4*)(Wn + (size_t)e * DDIM) + lane * 4;
        const f32x4* eq = (const f32x4*)(We + (size_t)e * DDIM) + lane * 4;
        const f32x4 w0 = wq[0], w1 = wq[1], w2 = wq[2], w3 = wq[3];
        const f32x4 e0 = eq[0], e1 = eq[1], e2 = eq[2], e3 = eq[3];
        double s = 0.0, t2 = 0.0;
#pragma unroll
        for (int i = 0; i < 4; i++) { s = fma((double)xv0[i], (double)w0[i], s); t2 = fma((double)xv0[i], (double)e0[i], t2); }
#pragma unroll
        for (int i = 0; i < 4; i++) { s = fma((double)xv1[i], (double)w1[i], s); t2 = fma((double)xv1[i], (double)e1[i], t2); }
#pragma unroll
        for (int i = 0; i < 4; i++) { s = fma((double)xv2[i], (double)w2[i], s); t2 = fma((double)xv2[i], (double)e2[i], t2); }
#pragma unroll
        for (int i = 0; i < 4; i++) { s = fma((double)xv3[i], (double)w3[i], s); t2 = fma((double)xv3[i], (double)e3[i], t2); }
#pragma unroll
        for (int off = 32; off > 0; off >>= 1) { s += __shfl_xor(s, off); t2 += __shfl_xor(t2, off); }
        s += (double)bn[e];
        if (lane == e) { v = (float)s; g = (float)t2; }
    }
    process_row(r, v, g, lane, x, Wn, bn, out);
}

extern "C" void kernel_launch(void* const* d_in, const int* in_sizes, int n_in,
                              void* d_out, int out_size, void* d_ws, size_t ws_size,
                              hipStream_t stream)
{
    // setup_inputs order: x, Wg, bg, Wn, bn, We, noise  (Wg/bg/noise are dead code)
    const float* x  = (const float*)d_in[0];
    const float* Wn = (const float*)d_in[3];
    const float* bn = (const float*)d_in[4];
    const float* We = (const float*)d_in[5];
    float* out = (float*)d_out;

    const int B = in_sizes[0] / DDIM;                       // 65536
    const size_t logBytes = (size_t)B * NEXP * sizeof(float);   // 16 MB
    const size_t need = (size_t)WSLOG_OFF + 2 * logBytes;       // ~34 MB

    if (d_ws != nullptr && ws_size >= need) {
        char*  wsW    = (char*)d_ws;
        float* ws_log = (float*)((char*)d_ws + WSLOG_OFF);
        float* ws_exp = (float*)((char*)d_ws + WSLOG_OFF + logBytes);
        conv_w_kernel<<<(NEXP * DDIM / 8) / 256, 256, 0, stream>>>(Wn, We, wsW);
        gemm_kernel<<<B / 64, 256, 0, stream>>>(x, wsW, ws_log, ws_exp);
        select_kernel<<<B / 128, 256, 0, stream>>>(x, Wn, bn, ws_log, ws_exp, out);
    } else {
        fused_fallback<<<(B + 3) / 4, 256, 0, stream>>>(x, Wn, bn, We, out, B);
    }
}

// Round 10
// 115.514 us; speedup vs baseline: 2.7144x; 2.7144x over previous
//
#include <hip/hip_runtime.h>

#define DDIM 1024
#define NEXP 64
#define TOPK 8
#define BK 32
#define NTILE 32
#define WTILE 12288
#define TAUF 5.0e-3f
#define TAUB 1.0e-2f
#define WSLOG_OFF (512 * 1024)

typedef __attribute__((ext_vector_type(8))) short short8;
typedef __attribute__((ext_vector_type(4))) float f32x4;

static __device__ __forceinline__ unsigned int f2u(float f) { return __builtin_bit_cast(unsigned int, f); }
static __device__ __forceinline__ float u2f(unsigned int u) { return __builtin_bit_cast(float, u); }

static __device__ __forceinline__ unsigned short bf_hi_rne(float x) {
    unsigned int u = f2u(x);
    return (unsigned short)((u + (0x7FFFu + ((u >> 16) & 1u))) >> 16);
}

static __device__ __forceinline__ void split2(float x, unsigned short& h, unsigned short& l) {
    unsigned int u = f2u(x);
    unsigned int uh = (u + (0x7FFFu + ((u >> 16) & 1u))) & 0xFFFF0000u;
    h = (unsigned short)(uh >> 16);
    float rem = x - u2f(uh);
    l = (unsigned short)(f2u(rem) >> 16);
}

// K1: pre-permute W into the swizzled LDS image (R6 layout), copied linearly by K2.
// tile t, array a (0=wn_hi,1=wn_lo,2=we_hi), expert e, 16B chunk c:
//   ws byte = t*12288 + a*4096 + ((e*64 + c*16) ^ ((e&7)<<4))
__global__ __launch_bounds__(256) void conv_w_kernel(
    const float* __restrict__ Wn, const float* __restrict__ We, char* __restrict__ wsW)
{
    int g = blockIdx.x * 256 + threadIdx.x;   // 0..8191
    int e = g >> 7, c128 = g & 127;
    int k = c128 << 3;
    int t = k >> 5, c = (k >> 3) & 3;
    const float* np = Wn + (size_t)e * DDIM + k;
    const float* ep = We + (size_t)e * DDIM + k;
    f32x4 n0 = ((const f32x4*)np)[0], n1 = ((const f32x4*)np)[1];
    f32x4 e0 = ((const f32x4*)ep)[0], e1 = ((const f32x4*)ep)[1];
    short8 nh, nl, eh;
#pragma unroll
    for (int i = 0; i < 4; i++) { unsigned short h, l; split2(n0[i], h, l); nh[i] = (short)h; nl[i] = (short)l; }
#pragma unroll
    for (int i = 0; i < 4; i++) { unsigned short h, l; split2(n1[i], h, l); nh[i + 4] = (short)h; nl[i + 4] = (short)l; }
#pragma unroll
    for (int i = 0; i < 4; i++) eh[i] = (short)bf_hi_rne(e0[i]);
#pragma unroll
    for (int i = 0; i < 4; i++) eh[i + 4] = (short)bf_hi_rne(e1[i]);
    size_t dst = (size_t)t * WTILE + (size_t)((e * 64 + c * 16) ^ ((e & 7) << 4));
    *(short8*)(wsW + dst)        = nh;
    *(short8*)(wsW + dst + 4096) = nl;
    *(short8*)(wsW + dst + 8192) = eh;
}

// ---- wave helpers (fallback path only)
static __device__ __forceinline__ float wave_maxf(float c) {
#pragma unroll
    for (int off = 32; off >= 1; off >>= 1) c = fmaxf(c, __shfl_xor(c, off));
    return c;
}
static __device__ __forceinline__ float wave_sumf(float c) {
#pragma unroll
    for (int off = 32; off >= 1; off >>= 1) c += __shfl_xor(c, off);
    return c;
}

static __device__ __forceinline__ void process_row(
    int r, float v, float g, int lane,
    const float* __restrict__ x, const float* __restrict__ Wn,
    const float* __restrict__ bn, float* __restrict__ out)
{
    for (int pass = 0; pass < 2; ++pass) {
        unsigned long long act = ~0ull, sel = 0ull;
        float m0 = 0.f, v8 = 0.f;
#pragma unroll
        for (int tt = 0; tt < TOPK; tt++) {
            float c = ((act >> lane) & 1ull) ? v : -3.0e38f;
            c = wave_maxf(c);
            unsigned long long elig = __ballot(v == c) & act;
            int win = __builtin_ctzll(elig);
            sel |= 1ull << win;
            act &= ~(1ull << win);
            if (tt == 0) m0 = c;
            v8 = c;
        }
        float c9 = ((act >> lane) & 1ull) ? v : -3.0e38f;
        float v9 = wave_maxf(c9);
        if (pass == 0 && (v8 - v9) < TAUF) {
            const float vb = 0.5f * (v8 + v9);
            unsigned long long cand = __ballot(fabsf(v - vb) <= TAUB);
            const f32x4* xq = (const f32x4*)(x + (size_t)r * DDIM) + lane * 4;
            const f32x4 xv0 = xq[0], xv1 = xq[1], xv2 = xq[2], xv3 = xq[3];
            while (cand) {
                const int ce = __builtin_ctzll(cand);
                cand &= cand - 1;
                const f32x4* wq = (const f32x4*)(Wn + (size_t)ce * DDIM) + lane * 4;
                const f32x4 w0 = wq[0], w1 = wq[1], w2 = wq[2], w3 = wq[3];
                double s = 0.0;
#pragma unroll
                for (int i = 0; i < 4; i++) s = fma((double)xv0[i], (double)w0[i], s);
#pragma unroll
                for (int i = 0; i < 4; i++) s = fma((double)xv1[i], (double)w1[i], s);
#pragma unroll
                for (int i = 0; i < 4; i++) s = fma((double)xv2[i], (double)w2[i], s);
#pragma unroll
                for (int i = 0; i < 4; i++) s = fma((double)xv3[i], (double)w3[i], s);
#pragma unroll
                for (int off = 32; off > 0; off >>= 1) s += __shfl_xor(s, off);
                s += (double)bn[ce];
                if (lane == ce) v = (float)s;
            }
            continue;
        }
        float w = ((sel >> lane) & 1ull) ? __expf(v - m0) : 0.f;
        float Z = wave_sumf(w);
        float O = wave_sumf(w * g);
        if (lane == 0) out[r] = O / Z;
        return;
    }
}

// K2: GEMM only. 64 rows/block, 1024 blocks, 256 thr, LDS 32768 B.
// ONLY change vs R9: __launch_bounds__(256,4) -> VGPR cap 128, no scratch spill.
__global__ __launch_bounds__(256, 4) void gemm_kernel(
    const float* __restrict__ x, const char* __restrict__ wsW,
    float* __restrict__ ws_log, float* __restrict__ ws_exp)
{
    __shared__ __align__(16) char smem[32768];

    const int tid = threadIdx.x;
    const int wid = tid >> 6;
    const int lane = tid & 63;
    const int fr = lane & 15;
    const int fq = lane >> 4;
    const int blockRow = blockIdx.x * 64;

    const int srow = tid >> 2, sg = tid & 3;
    const int swz = (srow * 64 + sg * 16) ^ ((srow & 7) << 4);
    const float* xsrc = x + (size_t)(blockRow + srow) * DDIM + sg * 8;
    const char* wsrc = wsW + tid * 16;

    const int ecol = wid * 16 + fr;
    const int woff = (ecol * 64 + fq * 16) ^ ((ecol & 7) << 4);

    f32x4 xA0, xA1, xB0, xB1, xC0, xC1;
    short8 wA0, wA1, wA2, wB0, wB1, wB2;

    f32x4 accN[4], accE[4];
#pragma unroll
    for (int rt = 0; rt < 4; rt++) { accN[rt] = f32x4{0.f,0.f,0.f,0.f}; accE[rt] = f32x4{0.f,0.f,0.f,0.f}; }

#define XL(S, T) { const float* p_ = xsrc + (T) * BK; \
    x##S##0 = ((const f32x4*)p_)[0]; x##S##1 = ((const f32x4*)p_)[1]; }
#define WL(S, T) { const char* q_ = wsrc + (size_t)(T) * WTILE; \
    w##S##0 = *(const short8*)(q_); \
    w##S##1 = *(const short8*)(q_ + 4096); \
    w##S##2 = *(const short8*)(q_ + 8192); }
#define SW(B, XS, WS) { short8 h_; \
    _Pragma("unroll") for (int i = 0; i < 4; i++) h_[i]     = (short)bf_hi_rne(x##XS##0[i]); \
    _Pragma("unroll") for (int i = 0; i < 4; i++) h_[i + 4] = (short)bf_hi_rne(x##XS##1[i]); \
    *(short8*)(smem + (B) * 4096 + swz) = h_; \
    char* wb_ = smem + 8192 + (B) * WTILE + tid * 16; \
    *(short8*)(wb_)        = w##WS##0; \
    *(short8*)(wb_ + 4096) = w##WS##1; \
    *(short8*)(wb_ + 8192) = w##WS##2; }
#define CP(B) { const char* wb_ = smem + 8192 + (B) * WTILE + woff; \
    short8 wh_ = *(const short8*)(wb_); \
    short8 wl_ = *(const short8*)(wb_ + 4096); \
    short8 eh_ = *(const short8*)(wb_ + 8192); \
    _Pragma("unroll") \
    for (int rt = 0; rt < 4; rt++) { \
        const int row_ = rt * 16 + fr; \
        const int xoff_ = (row_ * 64 + fq * 16) ^ ((row_ & 7) << 4); \
        short8 xh_ = *(const short8*)(smem + (B) * 4096 + xoff_); \
        accN[rt] = __builtin_amdgcn_mfma_f32_16x16x32_bf16(xh_, wh_, accN[rt], 0, 0, 0); \
        accN[rt] = __builtin_amdgcn_mfma_f32_16x16x32_bf16(xh_, wl_, accN[rt], 0, 0, 0); \
        accE[rt] = __builtin_amdgcn_mfma_f32_16x16x32_bf16(xh_, eh_, accE[rt], 0, 0, 0); \
    } }
#define BARR { asm volatile("s_waitcnt lgkmcnt(0)" ::: "memory"); \
               __builtin_amdgcn_s_barrier(); \
               asm volatile("" ::: "memory"); }

#define ITER(T, XS, WS, DOX, DOW) { \
    CP((T) & 1) \
    SW(((T) + 1) & 1, XS, WS) \
    if (DOX) { XL(XS, (T) + 4) } \
    if (DOW) { WL(WS, (T) + 3) } \
    BARR }

    XL(A, 0) XL(B, 1) XL(C, 2) WL(A, 0) WL(B, 1)
    SW(0, A, A)
    XL(A, 3) WL(A, 2)
    BARR

    ITER(0,  B, B, 1, 1) ITER(1,  C, A, 1, 1) ITER(2,  A, B, 1, 1)
    ITER(3,  B, A, 1, 1) ITER(4,  C, B, 1, 1) ITER(5,  A, A, 1, 1)
    ITER(6,  B, B, 1, 1) ITER(7,  C, A, 1, 1) ITER(8,  A, B, 1, 1)
    ITER(9,  B, A, 1, 1) ITER(10, C, B, 1, 1) ITER(11, A, A, 1, 1)
    ITER(12, B, B, 1, 1) ITER(13, C, A, 1, 1) ITER(14, A, B, 1, 1)
    ITER(15, B, A, 1, 1) ITER(16, C, B, 1, 1) ITER(17, A, A, 1, 1)
    ITER(18, B, B, 1, 1) ITER(19, C, A, 1, 1) ITER(20, A, B, 1, 1)
    ITER(21, B, A, 1, 1) ITER(22, C, B, 1, 1) ITER(23, A, A, 1, 1)
    ITER(24, B, B, 1, 1) ITER(25, C, A, 1, 1) ITER(26, A, B, 1, 1)
    ITER(27, B, A, 1, 1) ITER(28, C, B, 0, 1) ITER(29, A, A, 0, 0)
    ITER(30, B, B, 0, 0)
    CP(1)
    __syncthreads();

    float* sl = (float*)smem;                    // [64][64]
    float* se = (float*)(smem + 16384);          // [64][64]
#pragma unroll
    for (int rt = 0; rt < 4; rt++) {
#pragma unroll
        for (int j = 0; j < 4; j++) {
            const int r = rt * 16 + fq * 4 + j;  // C/D: col=lane&15, row=(lane>>4)*4+j
            sl[r * 64 + ecol] = accN[rt][j];
            se[r * 64 + ecol] = accE[rt][j];
        }
    }
    __syncthreads();
    {
        const int row = tid >> 2, cg = (tid & 3) * 16;
        float* gl = ws_log + (size_t)(blockRow + row) * 64 + cg;
        float* ge = ws_exp + (size_t)(blockRow + row) * 64 + cg;
#pragma unroll
        for (int i = 0; i < 4; i++) ((f32x4*)gl)[i] = *(const f32x4*)(sl + row * 64 + cg + i * 4);
#pragma unroll
        for (int i = 0; i < 4; i++) ((f32x4*)ge)[i] = *(const f32x4*)(se + row * 64 + cg + i * 4);
    }
}

// K3 v2: thread-per-row selection. 1024 blocks x 64 threads; lane owns row base+lane.
// Branchless 9-reg insertion ladder (zero cross-lane ops in the hot path).
__global__ __launch_bounds__(64) void select_kernel(
    const float* __restrict__ x, const float* __restrict__ Wn, const float* __restrict__ bn,
    const float* __restrict__ ws_log, const float* __restrict__ ws_exp, float* __restrict__ out)
{
    __shared__ float sv[64 * 65];
    __shared__ float sg[64 * 65];
    const int lane = threadIdx.x & 63;
    const int base = blockIdx.x * 64;

    // stage 64 rows coalesced (f32x4), fold bias into sv
    const int sr = lane >> 4;            // 0..3
    const int sc = (lane & 15) * 4;      // 0,4,..,60
    const f32x4 bnv = *(const f32x4*)(bn + sc);
#pragma unroll
    for (int g = 0; g < 16; ++g) {
        const int row = g * 4 + sr;
        f32x4 lv = *(const f32x4*)(ws_log + (size_t)(base + row) * 64 + sc);
        f32x4 gv = *(const f32x4*)(ws_exp + (size_t)(base + row) * 64 + sc);
        lv = lv + bnv;
        *(f32x4*)(sv + row * 65 + sc) = lv;
        *(f32x4*)(sg + row * 65 + sc) = gv;
    }
    __syncthreads();

    const float* vrow = sv + lane * 65;
    const float* grow = sg + lane * 65;

    float l0, l1, l2, l3, l4, l5, l6, l7, l8;
#define INS(v) { float t_ = (v), h_; \
    h_ = fmaxf(l0, t_); t_ = fminf(l0, t_); l0 = h_; \
    h_ = fmaxf(l1, t_); t_ = fminf(l1, t_); l1 = h_; \
    h_ = fmaxf(l2, t_); t_ = fminf(l2, t_); l2 = h_; \
    h_ = fmaxf(l3, t_); t_ = fminf(l3, t_); l3 = h_; \
    h_ = fmaxf(l4, t_); t_ = fminf(l4, t_); l4 = h_; \
    h_ = fmaxf(l5, t_); t_ = fminf(l5, t_); l5 = h_; \
    h_ = fmaxf(l6, t_); t_ = fminf(l6, t_); l6 = h_; \
    h_ = fmaxf(l7, t_); t_ = fminf(l7, t_); l7 = h_; \
    l8 = fmaxf(l8, t_); }
#define LADDER { \
    l0 = l1 = l2 = l3 = l4 = l5 = l6 = l7 = l8 = -3.0e38f; \
    _Pragma("unroll") \
    for (int c_ = 0; c_ < 16; ++c_) { \
        f32x4 vv_ = *(const f32x4*)(vrow + c_ * 4); \
        INS(vv_[0]) INS(vv_[1]) INS(vv_[2]) INS(vv_[3]) \
    } }

    LADDER
    const float gap = l7 - l8;
    const float vb = 0.5f * (l7 + l8);
    const bool flg = gap < TAUF;
    unsigned long long fm = __ballot(flg);

    // fp64 fixup for near-tie rows (wave-cooperative, rare)
    while (fm) {
        const int rl = __builtin_ctzll(fm);
        fm &= fm - 1;
        const float vbr = __shfl(vb, rl);
        const float ve = sv[rl * 65 + lane];
        unsigned long long cand = __ballot(fabsf(ve - vbr) <= TAUB);
        const f32x4* xq = (const f32x4*)(x + (size_t)(base + rl) * DDIM) + lane * 4;
        const f32x4 xv0 = xq[0], xv1 = xq[1], xv2 = xq[2], xv3 = xq[3];
        while (cand) {
            const int ce = __builtin_ctzll(cand);
            cand &= cand - 1;
            const f32x4* wq = (const f32x4*)(Wn + (size_t)ce * DDIM) + lane * 4;
            const f32x4 w0 = wq[0], w1 = wq[1], w2 = wq[2], w3 = wq[3];
            double s = 0.0;
#pragma unroll
            for (int i = 0; i < 4; i++) s = fma((double)xv0[i], (double)w0[i], s);
#pragma unroll
            for (int i = 0; i < 4; i++) s = fma((double)xv1[i], (double)w1[i], s);
#pragma unroll
            for (int i = 0; i < 4; i++) s = fma((double)xv2[i], (double)w2[i], s);
#pragma unroll
            for (int i = 0; i < 4; i++) s = fma((double)xv3[i], (double)w3[i], s);
#pragma unroll
            for (int off = 32; off > 0; off >>= 1) s += __shfl_xor(s, off);
            s += (double)bn[ce];
            if (lane == 0) sv[rl * 65 + ce] = (float)s;
        }
    }
    __syncthreads();
    if (flg) { LADDER }

    const float th = l7, m0 = l0;
    float Z = 0.f, O = 0.f;
    int ngt = 0;
#pragma unroll
    for (int c = 0; c < 16; ++c) {
        f32x4 vv = *(const f32x4*)(vrow + c * 4);
        f32x4 gg = *(const f32x4*)(grow + c * 4);
#pragma unroll
        for (int j = 0; j < 4; j++) {
            const float v = vv[j];
            if (v > th) { const float w = __expf(v - m0); Z += w; O += w * gg[j]; ngt++; }
        }
    }
    // ties at threshold: lowest index wins (scan in index order)
    int need = TOPK - ngt;
    for (int c = 0; c < 16 && need > 0; ++c) {
        f32x4 vv = *(const f32x4*)(vrow + c * 4);
        f32x4 gg = *(const f32x4*)(grow + c * 4);
#pragma unroll
        for (int j = 0; j < 4; j++) {
            if (vv[j] == th && need > 0) { const float w = __expf(vv[j] - m0); Z += w; O += w * gg[j]; need--; }
        }
    }
    out[base + lane] = O / Z;
}

// Fallback (ws too small): exact fp64 per-row computation. Slow but correct.
__global__ __launch_bounds__(256) void fused_fallback(
    const float* __restrict__ x, const float* __restrict__ Wn, const float* __restrict__ bn,
    const float* __restrict__ We, float* __restrict__ out, int B)
{
    const int wid = threadIdx.x >> 6, lane = threadIdx.x & 63;
    const int r = blockIdx.x * 4 + wid;
    if (r >= B) return;
    const f32x4* xq = (const f32x4*)(x + (size_t)r * DDIM) + lane * 4;
    const f32x4 xv0 = xq[0], xv1 = xq[1], xv2 = xq[2], xv3 = xq[3];
    float v = 0.f, g = 0.f;
    for (int e = 0; e < NEXP; ++e) {
        const f32x4* wq = (const f32x4*)(Wn + (size_t)e * DDIM) + lane * 4;
        const f32x4* eq = (const f32x4*)(We + (size_t)e * DDIM) + lane * 4;
        const f32x4 w0 = wq[0], w1 = wq[1], w2 = wq[2], w3 = wq[3];
        const f32x4 e0 = eq[0], e1 = eq[1], e2 = eq[2], e3 = eq[3];
        double s = 0.0, t2 = 0.0;
#pragma unroll
        for (int i = 0; i < 4; i++) { s = fma((double)xv0[i], (double)w0[i], s); t2 = fma((double)xv0[i], (double)e0[i], t2); }
#pragma unroll
        for (int i = 0; i < 4; i++) { s = fma((double)xv1[i], (double)w1[i], s); t2 = fma((double)xv1[i], (double)e1[i], t2); }
#pragma unroll
        for (int i = 0; i < 4; i++) { s = fma((double)xv2[i], (double)w2[i], s); t2 = fma((double)xv2[i], (double)e2[i], t2); }
#pragma unroll
        for (int i = 0; i < 4; i++) { s = fma((double)xv3[i], (double)w3[i], s); t2 = fma((double)xv3[i], (double)e3[i], t2); }
#pragma unroll
        for (int off = 32; off > 0; off >>= 1) { s += __shfl_xor(s, off); t2 += __shfl_xor(t2, off); }
        s += (double)bn[e];
        if (lane == e) { v = (float)s; g = (float)t2; }
    }
    process_row(r, v, g, lane, x, Wn, bn, out);
}

extern "C" void kernel_launch(void* const* d_in, const int* in_sizes, int n_in,
                              void* d_out, int out_size, void* d_ws, size_t ws_size,
                              hipStream_t stream)
{
    // setup_inputs order: x, Wg, bg, Wn, bn, We, noise  (Wg/bg/noise are dead code)
    const float* x  = (const float*)d_in[0];
    const float* Wn = (const float*)d_in[3];
    const float* bn = (const float*)d_in[4];
    const float* We = (const float*)d_in[5];
    float* out = (float*)d_out;

    const int B = in_sizes[0] / DDIM;                           // 65536
    const size_t logBytes = (size_t)B * NEXP * sizeof(float);   // 16 MB
    const size_t need = (size_t)WSLOG_OFF + 2 * logBytes;       // ~34 MB

    if (d_ws != nullptr && ws_size >= need) {
        char*  wsW    = (char*)d_ws;
        float* ws_log = (float*)((char*)d_ws + WSLOG_OFF);
        float* ws_exp = (float*)((char*)d_ws + WSLOG_OFF + logBytes);
        conv_w_kernel<<<(NEXP * DDIM / 8) / 256, 256, 0, stream>>>(Wn, We, wsW);
        gemm_kernel<<<B / 64, 256, 0, stream>>>(x, wsW, ws_log, ws_exp);
        select_kernel<<<B / 64, 64, 0, stream>>>(x, Wn, bn, ws_log, ws_exp, out);
    } else {
        fused_fallback<<<(B + 3) / 4, 256, 0, stream>>>(x, Wn, bn, We, out, B);
    }
}